// Round 6
// baseline (418.611 us; speedup 1.0000x reference)
//
#include <hip/hip_runtime.h>
#include <math.h>

#define N_NODES  50000
#define N_EDGES  800000
#define HIDDEN   128
#define N_LAYERS 3
#define N_MASKED 25000
#define N_GRAPHS 64

// ordered float<->uint mapping (monotonic): preserves IEEE total order
__device__ __forceinline__ unsigned fmap(float f) {
    unsigned u = __float_as_uint(f);
    return (u & 0x80000000u) ? ~u : (u | 0x80000000u);
}
__device__ __forceinline__ float funmap(unsigned u) {
    return __uint_as_float((u & 0x80000000u) ? (u & 0x7FFFFFFFu) : ~u);
}

// ---------------- degree count (in-degree via dst) ----------------
__global__ void count_deg_kernel(const int* __restrict__ dst, unsigned* __restrict__ deg) {
    int i = blockIdx.x * blockDim.x + threadIdx.x;
    if (i < N_EDGES) atomicAdd(&deg[dst[i]], 1u);
}

__global__ void dinv_kernel(const unsigned* __restrict__ deg, float* __restrict__ dinv) {
    int i = blockIdx.x * blockDim.x + threadIdx.x;
    if (i < N_NODES) dinv[i] = rsqrtf((float)(deg[i] + 1u));   // +1 self-loop
}

// ---------------- prefix sum: per-block inclusive scan ----------------
__global__ void scan_block_kernel(const unsigned* __restrict__ deg, unsigned* __restrict__ incl,
                                  unsigned* __restrict__ bsum) {
    __shared__ unsigned s[1024];
    int i = blockIdx.x * 1024 + threadIdx.x;
    unsigned v = (i < N_NODES) ? deg[i] : 0u;
    s[threadIdx.x] = v;
    __syncthreads();
    for (int off = 1; off < 1024; off <<= 1) {
        unsigned t = (threadIdx.x >= off) ? s[threadIdx.x - off] : 0u;
        __syncthreads();
        s[threadIdx.x] += t;
        __syncthreads();
    }
    if (i < N_NODES) incl[i] = s[threadIdx.x];
    if (threadIdx.x == 1023) bsum[blockIdx.x] = s[1023];
}

__global__ void scan_bsum_kernel(unsigned* __restrict__ bsum, int n) {
    if (blockIdx.x == 0 && threadIdx.x == 0) {
        unsigned run = 0;
        for (int i = 0; i < n; ++i) { unsigned t = bsum[i]; bsum[i] = run; run += t; }
    }
}

__global__ void scan_finalize_kernel(const unsigned* __restrict__ incl,
                                     const unsigned* __restrict__ bsum_ex,
                                     unsigned* __restrict__ row_ptr,
                                     unsigned* __restrict__ cursor) {
    int i = blockIdx.x * blockDim.x + threadIdx.x;
    if (i <= N_NODES) {
        unsigned v = (i == 0) ? 0u : incl[i - 1] + bsum_ex[(i - 1) >> 10];
        row_ptr[i] = v;
        if (i < N_NODES) cursor[i] = v;
    }
}

// ---------------- CSR fill ----------------
__global__ void fill_csr_kernel(const int* __restrict__ src, const int* __restrict__ dst,
                                unsigned* __restrict__ cursor, int* __restrict__ csr_src) {
    int e = blockIdx.x * blockDim.x + threadIdx.x;
    if (e < N_EDGES) {
        unsigned p = atomicAdd(&cursor[dst[e]], 1u);
        csr_src[p] = src[e];
    }
}

// ---------------- GEMM + row-scale: Out[r][:] = dinv[r] * (A[r][:] @ W) ----------------
__global__ __launch_bounds__(256, 2) void gemm128_kernel(const float* __restrict__ A,
                                                         const float* __restrict__ W,
                                                         const float* __restrict__ dinv,
                                                         float* __restrict__ Out,
                                                         int nrows) {
    __shared__ float Wl[128 * 128];   // 64 KB
    __shared__ float Rb[32 * 128];    // 16 KB
    const int tid = threadIdx.x;

    for (int i = tid * 4; i < 128 * 128; i += 256 * 4)
        *(float4*)&Wl[i] = *(const float4*)&W[i];
    __syncthreads();

    const int c4 = (tid & 31) * 4;
    const int rr = tid >> 5;

    for (int rowBase = blockIdx.x * 32; rowBase < nrows; rowBase += gridDim.x * 32) {
        for (int i = tid * 4; i < 32 * 128; i += 256 * 4) {
            int row = rowBase + (i >> 7);
            float4 v = make_float4(0.f, 0.f, 0.f, 0.f);
            if (row < nrows) v = *(const float4*)&A[(size_t)row * 128 + (i & 127)];
            *(float4*)&Rb[i] = v;
        }
        __syncthreads();

        float4 acc[4];
        #pragma unroll
        for (int m = 0; m < 4; ++m) acc[m] = make_float4(0, 0, 0, 0);

        #pragma unroll 4
        for (int k4 = 0; k4 < 128; k4 += 4) {
            float h0[4], h1[4], h2[4], h3[4];
            *(float4*)h0 = *(const float4*)&Rb[(rr +  0) * 128 + k4];
            *(float4*)h1 = *(const float4*)&Rb[(rr +  8) * 128 + k4];
            *(float4*)h2 = *(const float4*)&Rb[(rr + 16) * 128 + k4];
            *(float4*)h3 = *(const float4*)&Rb[(rr + 24) * 128 + k4];
            #pragma unroll
            for (int j = 0; j < 4; ++j) {
                float4 wv = *(const float4*)&Wl[(k4 + j) * 128 + c4];
                acc[0].x += h0[j] * wv.x; acc[0].y += h0[j] * wv.y;
                acc[0].z += h0[j] * wv.z; acc[0].w += h0[j] * wv.w;
                acc[1].x += h1[j] * wv.x; acc[1].y += h1[j] * wv.y;
                acc[1].z += h1[j] * wv.z; acc[1].w += h1[j] * wv.w;
                acc[2].x += h2[j] * wv.x; acc[2].y += h2[j] * wv.y;
                acc[2].z += h2[j] * wv.z; acc[2].w += h2[j] * wv.w;
                acc[3].x += h3[j] * wv.x; acc[3].y += h3[j] * wv.y;
                acc[3].z += h3[j] * wv.z; acc[3].w += h3[j] * wv.w;
            }
        }

        #pragma unroll
        for (int m = 0; m < 4; ++m) {
            int r0 = rowBase + rr + m * 8;
            if (r0 < nrows) {
                float d = dinv[r0];
                float4 o = acc[m];
                o.x *= d; o.y *= d; o.z *= d; o.w *= d;
                *(float4*)&Out[(size_t)r0 * 128 + c4] = o;
            }
        }
        __syncthreads();
    }
}

// ---------------- CSR gather over pre-scaled rows ----------------
// ONE WAVE PER ITEM (whole 128-f row, float2 per lane) — halves HBM fetch vs
// half-row waves (each source row fetched once, not twice). 8-deep chains.
// o = dinv[v] * (hws[v] + sum_{s in N(v)} hws[s]) + bias; ELU.
// gmax==nullptr: write out[w]. Else v=nodes[w], g=batch[w]: atomicMax fmap(o).
__global__ __launch_bounds__(256) void gather_kernel(const float* __restrict__ hws,
                                                     const unsigned* __restrict__ row_ptr,
                                                     const int* __restrict__ csr_src,
                                                     const float* __restrict__ dinv,
                                                     const float* __restrict__ bias,
                                                     float* __restrict__ out,
                                                     const int* __restrict__ nodes,
                                                     const int* __restrict__ batch,
                                                     unsigned* __restrict__ gmax,
                                                     int n_items) {
    int w = (blockIdx.x * blockDim.x + threadIdx.x) >> 6;
    if (w >= n_items) return;
    const int lane = threadIdx.x & 63;
    const int v = nodes ? nodes[w] : w;

    const unsigned s0 = row_ptr[v], e0 = row_ptr[v + 1];
    const float2* __restrict__ base = (const float2*)hws + lane;  // row r at base[r*64]

    float ax[8], ay[8];
    #pragma unroll
    for (int j = 0; j < 8; ++j) { ax[j] = 0.f; ay[j] = 0.f; }
    {
        float2 t = base[(size_t)v << 6];   // self-loop row
        ax[0] = t.x; ay[0] = t.y;
    }

    unsigned i = s0;
    if (i + 8 <= e0) {
        int idx[8];
        #pragma unroll
        for (int j = 0; j < 8; ++j) idx[j] = csr_src[i + j];
        for (; i + 16 <= e0; i += 8) {
            int nxt[8];
            #pragma unroll
            for (int j = 0; j < 8; ++j) nxt[j] = csr_src[i + 8 + j];
            #pragma unroll
            for (int j = 0; j < 8; ++j) {
                float2 t = base[(size_t)idx[j] << 6];
                ax[j] += t.x; ay[j] += t.y;
            }
            #pragma unroll
            for (int j = 0; j < 8; ++j) idx[j] = nxt[j];
        }
        #pragma unroll
        for (int j = 0; j < 8; ++j) {
            float2 t = base[(size_t)idx[j] << 6];
            ax[j] += t.x; ay[j] += t.y;
        }
        i += 8;
    }
    if (i + 4 <= e0) {
        #pragma unroll
        for (int j = 0; j < 4; ++j) {
            float2 t = base[(size_t)csr_src[i + j] << 6];
            ax[j] += t.x; ay[j] += t.y;
        }
        i += 4;
    }
    for (; i < e0; ++i) {
        float2 t = base[(size_t)csr_src[i] << 6];
        ax[0] += t.x; ay[0] += t.y;
    }

    float dv = dinv[v];
    float2 bb = ((const float2*)bias)[lane];
    float ox = dv * (((ax[0] + ax[1]) + (ax[2] + ax[3])) +
                     ((ax[4] + ax[5]) + (ax[6] + ax[7]))) + bb.x;
    float oy = dv * (((ay[0] + ay[1]) + (ay[2] + ay[3])) +
                     ((ay[4] + ay[5]) + (ay[6] + ay[7]))) + bb.y;
    ox = ox > 0.f ? ox : expm1f(ox);
    oy = oy > 0.f ? oy : expm1f(oy);

    if (gmax) {
        int g = batch[w];
        atomicMax(&gmax[g * 128 + lane * 2],     fmap(ox));
        atomicMax(&gmax[g * 128 + lane * 2 + 1], fmap(oy));
    } else {
        ((float2*)out)[((size_t)w << 6) + lane] = make_float2(ox, oy);
    }
}

// ---------------- init gmax to mapped(-inf) ----------------
__global__ void gmax_init_kernel(unsigned* __restrict__ gmax) {
    int i = blockIdx.x * blockDim.x + threadIdx.x;
    if (i < N_GRAPHS * 128) gmax[i] = 0x007FFFFFu;  // fmap(-inf)
}

// ---------------- finish: out[g] = sum_f unmap(gmax[g][f]) * w[f] + b ----------------
__global__ void pool_finish_kernel(const unsigned* __restrict__ gmax,
                                   const float* __restrict__ w, const float* __restrict__ b,
                                   float* __restrict__ out) {
    const int g = blockIdx.x;
    const int f = threadIdx.x;
    float val = funmap(gmax[g * 128 + f]) * w[f];
    #pragma unroll
    for (int off = 32; off > 0; off >>= 1) val += __shfl_down(val, off);
    __shared__ float ps[2];
    if ((threadIdx.x & 63) == 0) ps[threadIdx.x >> 6] = val;
    __syncthreads();
    if (threadIdx.x == 0) out[g] = ps[0] + ps[1] + b[0];
}

extern "C" void kernel_launch(void* const* d_in, const int* in_sizes, int n_in,
                              void* d_out, int out_size, void* d_ws, size_t ws_size,
                              hipStream_t stream) {
    const float* x      = (const float*)d_in[0];
    const int*   ei     = (const int*)d_in[1];
    const int*   mask   = (const int*)d_in[2];
    const int*   batch  = (const int*)d_in[3];
    const float* conv_w = (const float*)d_in[4];
    const float* conv_b = (const float*)d_in[5];
    const float* lt1_w  = (const float*)d_in[6];
    const float* lt1_b  = (const float*)d_in[7];
    float* out = (float*)d_out;

    const int* e_src = ei;
    const int* e_dst = ei + N_EDGES;

    // ---- workspace carve-up (aligned to 256B) ----
    char* ws = (char*)d_ws;
    auto carve = [&](size_t bytes) { char* p = ws; ws += (bytes + 255) & ~(size_t)255; return p; };
    unsigned* deg     = (unsigned*)carve(N_NODES * 4);
    float*    dinv    = (float*)   carve(N_NODES * 4);
    unsigned* row_ptr = (unsigned*)carve((N_NODES + 1) * 4);
    unsigned* cursor  = (unsigned*)carve(N_NODES * 4);
    unsigned* bsum    = (unsigned*)carve(64 * 4);
    unsigned* gmax    = (unsigned*)carve(N_GRAPHS * 128 * 4);
    int*      csr_src = (int*)     carve((size_t)N_EDGES * 4);
    float*    hws     = (float*)   carve((size_t)N_NODES * HIDDEN * 4);
    float*    hbuf    = (float*)   carve((size_t)N_NODES * HIDDEN * 4);
    unsigned* incl    = (unsigned*)csr_src;  // alias: dead before fill_csr runs

    const int NB_SCAN = (N_NODES + 1023) / 1024;  // 49

    // ---- build dinv + CSR ----
    hipMemsetAsync(deg, 0, N_NODES * sizeof(unsigned), stream);
    count_deg_kernel<<<(N_EDGES + 255) / 256, 256, 0, stream>>>(e_dst, deg);
    dinv_kernel<<<(N_NODES + 255) / 256, 256, 0, stream>>>(deg, dinv);
    scan_block_kernel<<<NB_SCAN, 1024, 0, stream>>>(deg, incl, bsum);
    scan_bsum_kernel<<<1, 64, 0, stream>>>(bsum, NB_SCAN);
    scan_finalize_kernel<<<(N_NODES + 256) / 256, 256, 0, stream>>>(incl, bsum, row_ptr, cursor);
    fill_csr_kernel<<<(N_EDGES + 255) / 256, 256, 0, stream>>>(e_src, e_dst, cursor, csr_src);
    gmax_init_kernel<<<(N_GRAPHS * 128 + 255) / 256, 256, 0, stream>>>(gmax);

    // ---- 3 GCN layers ----
    const float* h_in = x;
    for (int l = 0; l < N_LAYERS; ++l) {
        gemm128_kernel<<<512, 256, 0, stream>>>(h_in, conv_w + l * 128 * 128, dinv, hws, N_NODES);
        if (l < N_LAYERS - 1) {
            // one wave per node
            gather_kernel<<<(N_NODES * 64 + 255) / 256, 256, 0, stream>>>(
                hws, row_ptr, csr_src, dinv, conv_b + l * HIDDEN, hbuf,
                nullptr, nullptr, nullptr, N_NODES);
            h_in = hbuf;
        } else {
            gather_kernel<<<(N_MASKED * 64 + 255) / 256, 256, 0, stream>>>(
                hws, row_ptr, csr_src, dinv, conv_b + l * HIDDEN, nullptr,
                mask, batch, gmax, N_MASKED);
        }
    }

    pool_finish_kernel<<<N_GRAPHS, HIDDEN, 0, stream>>>(gmax, lt1_w, lt1_b, out);
}